// Round 6
// baseline (285.194 us; speedup 1.0000x reference)
//
#include <hip/hip_runtime.h>
#include <hip/hip_bf16.h>
#include <math.h>

// Problem constants
#define BB 2
#define MM 9          // 1 query + 8 supports
#define MS 8
#define DD 256
#define HW 2304       // 48*48
#define NCLS 4
#define OUTR 224

#define TOT_TILES (144 * 18 * BB)   // 5184 kgemm blocks
#define TAIL 64                     // blocks that perform the fused resize

typedef float floatx4 __attribute__((ext_vector_type(4)));
typedef __bf16 bf16x8 __attribute__((ext_vector_type(8)));
typedef unsigned short ushortx8 __attribute__((ext_vector_type(8)));

// order-preserving float <-> uint encode for atomicMax
__device__ __forceinline__ unsigned enc_f(float f) {
    unsigned u = __float_as_uint(f);
    return (u & 0x80000000u) ? ~u : (u | 0x80000000u);
}
__device__ __forceinline__ float dec_f(unsigned k) {
    unsigned u = (k & 0x80000000u) ? (k & 0x7FFFFFFFu) : ~k;
    return __uint_as_float(u);
}
__device__ __forceinline__ unsigned load_agent(const unsigned* p) {
    return __hip_atomic_load(p, __ATOMIC_RELAXED, __HIP_MEMORY_SCOPE_AGENT);
}

// ---------------- Kernel 1 (v3): v1 structure (32-pix tiles, 4 blocks/CU) + float4 loads -------
// in : emb[bm][d][pix] fp32 ; out: normed[bm][pix][d] bf16. Also zero-inits enc_logits + cnt.
__global__ __launch_bounds__(256) void knorm(const float* __restrict__ emb,
                                             __hip_bfloat16* __restrict__ outp,
                                             unsigned* __restrict__ enc_logits) {
    __shared__ float tile[256][33];   // [d][pix], +1 pad
    __shared__ float psum[8][32];
    __shared__ float sscale[32];
    const int bm   = blockIdx.y;
    const int pix0 = blockIdx.x * 32;
    const int tid  = threadIdx.x;

    // fused init of encoded logits + ticket counter (BB*NCLS*HW + 1 entries)
    int flat = (blockIdx.y * gridDim.x + blockIdx.x) * 256 + tid;
    if (flat < BB * NCLS * HW + 1) enc_logits[flat] = 0u;

    // ---- load: 8 iterations of float4; per iter wave covers 8 d-rows x 128B ----
    const float* src = emb + (size_t)bm * DD * HW + pix0;
    {
        const int dr = tid >> 3;          // 0..31
        const int p4 = (tid & 7) * 4;     // 0..28
#pragma unroll
        for (int r = 0; r < 8; ++r) {
            int d = r * 32 + dr;
            floatx4 v = *(const floatx4*)(src + (size_t)d * HW + p4);
            float* t = &tile[d][p4];
            t[0] = v[0]; t[1] = v[1]; t[2] = v[2]; t[3] = v[3];
        }
    }
    __syncthreads();
    // ---- sum of squares: thread (chunk=dr8, pix=pc) sums 32 d's ----
    {
        const int pc = tid & 31;
        const int dr = tid >> 5;          // 0..7
        float ss = 0.f;
#pragma unroll
        for (int s = 0; s < 32; ++s) {
            float v = tile[dr * 32 + s][pc];
            ss += v * v;
        }
        psum[dr][pc] = ss;
    }
    __syncthreads();
    if (tid < 32) {
        float t = 0.f;
#pragma unroll
        for (int c = 0; c < 8; ++c) t += psum[c][tid];
        sscale[tid] = 1.0f / fmaxf(sqrtf(t), 1e-12f);
    }
    __syncthreads();
    // ---- store: thread=d, r=pixel; 512B dense per r across the block ----
    __hip_bfloat16* dst = outp + (size_t)bm * HW * DD + (size_t)pix0 * DD;
#pragma unroll
    for (int r = 0; r < 32; ++r) {
        float v = tile[tid][r] * sscale[r];
        dst[(size_t)r * DD + tid] = __float2bfloat16(v);
    }
}

// ---------------- Kernel 2: bf16 MFMA GEMM + mask + masked max + atomicMax + fused resize tail -
__device__ __forceinline__ void gld16(const unsigned short* g, unsigned short* l) {
    __builtin_amdgcn_global_load_lds((__attribute__((address_space(1))) void*)g,
                                     (__attribute__((address_space(3))) void*)l, 16, 0, 0);
}

#define BK 64
#define REDSTRIDE 132
// LDS: staging As+Bs = 32768 B; epilogue red[2][32][132] f32 = 33792 B (union)
#define SMEM_BYTES 33792

// grid: (144 = m*18 + kt, 18 = row tile, 2 = b); block 256 (4 waves)
__global__ __launch_bounds__(256, 4) void kgemm(const unsigned short* __restrict__ normed,
                                                const float* __restrict__ pm,
                                                unsigned* __restrict__ enc_logits,
                                                unsigned* __restrict__ cnt,
                                                float* __restrict__ out) {
    __shared__ __attribute__((aligned(16))) unsigned char smem[SMEM_BYTES];
    __shared__ int ticket_s;
    unsigned short* As = (unsigned short*)smem;          // [128][64] row-major, chunk-swizzled
    unsigned short* Bs = As + 128 * 64;
    float* red = (float*)smem;                           // union (staging dead in epilogue)

    const int ct = blockIdx.x;       // 0..143
    const int rt = blockIdx.y;       // 0..17
    const int b  = blockIdx.z;
    const int m  = ct / 18;          // support index 0..7
    const int kt = ct % 18;          // col tile within support

    const int tid  = threadIdx.x;
    const int lane = tid & 63;
    const int wave = tid >> 6;
    const int wr = wave >> 1, wc = wave & 1;
    const int lrow = lane & 15;
    const int quad = lane >> 4;      // 0..3

    const unsigned short* A  = normed + (size_t)(b * MM) * (HW * DD) + (size_t)(rt * 128) * DD;
    const unsigned short* Bp = normed + (size_t)(b * MM + 1 + m) * (HW * DD) + (size_t)(kt * 128) * DD;

    // ---- fused mask bits ----
    const float* pmB = pm + (size_t)(b * MS + m) * NCLS * HW;
    int mj[4];
#pragma unroll
    for (int j = 0; j < 4; ++j) {
        int kp = kt * 128 + wc * 64 + j * 16 + lrow;
        float p1 = pmB[HW + kp], p2 = pmB[2 * HW + kp], p3 = pmB[3 * HW + kp];
        mj[j] = ((p1 + p2 + p3 == 0.0f) ? 1 : 0) | (p1 != 0.0f ? 2 : 0) |
                (p2 != 0.0f ? 4 : 0) | (p3 != 0.0f ? 8 : 0);
    }

    // staging: lane l covers row r0+(l>>3), phys chunk p=l&7 holds logical chunk p^(row&7).
    const int srq  = lane >> 3;                  // row within 8-row group
    const int scol = ((lane & 7) ^ srq) * 8;     // logical chunk * 8 elems

    floatx4 zero = {0.f, 0.f, 0.f, 0.f};
    floatx4 acc[4][4];
#pragma unroll
    for (int i = 0; i < 4; ++i)
#pragma unroll
        for (int j = 0; j < 4; ++j) acc[i][j] = zero;

    for (int k0 = 0; k0 < DD; k0 += BK) {
#pragma unroll
        for (int q = 0; q < 4; ++q) {
            int row = wave * 32 + q * 8 + srq;
            gld16(A  + (size_t)row * DD + k0 + scol, As + (wave * 4 + q) * 512);
            gld16(Bp + (size_t)row * DD + k0 + scol, Bs + (wave * 4 + q) * 512);
        }
        __syncthreads();
#pragma unroll
        for (int kk = 0; kk < 2; ++kk) {
            bf16x8 af[4], bfr[4];
#pragma unroll
            for (int i = 0; i < 4; ++i) {
                int ar = wr * 64 + i * 16 + lrow;
                int br = wc * 64 + i * 16 + lrow;
                int pcA = (kk * 4 + quad) ^ (ar & 7);   // phys chunk (swizzled)
                int pcB = (kk * 4 + quad) ^ (br & 7);
                af[i]  = __builtin_bit_cast(bf16x8, *(const ushortx8*)(As + ar * 64 + pcA * 8));
                bfr[i] = __builtin_bit_cast(bf16x8, *(const ushortx8*)(Bs + br * 64 + pcB * 8));
            }
#pragma unroll
            for (int i = 0; i < 4; ++i)
#pragma unroll
                for (int j = 0; j < 4; ++j)
                    acc[i][j] = __builtin_amdgcn_mfma_f32_16x16x32_bf16(af[i], bfr[j], acc[i][j], 0, 0, 0);
        }
        __syncthreads();
    }

    // ---- epilogue: per-class masked max, LDS transpose-reduce, atomicMax ----
    const int col32 = wc * 16 + lrow;

#pragma unroll
    for (int p = 0; p < 2; ++p) {
        if (p) __syncthreads();
        bool bit[2][4];
#pragma unroll
        for (int nn = 0; nn < 2; ++nn) {
            int n = p * 2 + nn;
#pragma unroll
            for (int j = 0; j < 4; ++j) bit[nn][j] = (mj[j] >> n) & 1;
        }
#pragma unroll
        for (int nn = 0; nn < 2; ++nn) {
#pragma unroll
            for (int i = 0; i < 4; ++i) {
                floatx4 o;
#pragma unroll
                for (int r = 0; r < 4; ++r) {
                    float t0 = bit[nn][0] ? acc[i][0][r] : -INFINITY;
                    float t1 = bit[nn][1] ? acc[i][1][r] : -INFINITY;
                    float t2 = bit[nn][2] ? acc[i][2][r] : -INFINITY;
                    float t3 = bit[nn][3] ? acc[i][3][r] : -INFINITY;
                    o[r] = fmaxf(fmaxf(t0, t1), fmaxf(t2, t3));
                }
                int rowbase = wr * 64 + i * 16 + quad * 4;
                *(floatx4*)(red + ((size_t)(nn * 32 + col32)) * REDSTRIDE + rowbase) = o;
            }
        }
        __syncthreads();
        {
            int nn  = tid >> 7;
            int row = tid & 127;
            float v = -INFINITY;
#pragma unroll
            for (int c = 0; c < 32; ++c)
                v = fmaxf(v, red[((size_t)(nn * 32 + c)) * REDSTRIDE + row]);
            int n = p * 2 + nn;
            atomicMax(enc_logits + ((size_t)b * NCLS + n) * HW + rt * 128 + row, enc_f(v));
        }
    }

    // ---- fused resize tail: last TAIL blocks do the bilinear upsample ----
    __syncthreads();
    if (tid == 0) {
        __threadfence();                       // release our enc atomics before ticketing
        ticket_s = (int)atomicAdd(cnt, 1u);
    }
    __syncthreads();
    const int ticket = ticket_s;
    if (ticket < TOT_TILES - TAIL) return;
    if (tid == 0) {
        // Safe: by the time the last TAIL tickets are issued, every block has reached
        // its ticket add, so cnt is guaranteed to reach TOT_TILES -> no deadlock.
        while (__hip_atomic_load(cnt, __ATOMIC_ACQUIRE, __HIP_MEMORY_SCOPE_AGENT) < TOT_TILES)
            __builtin_amdgcn_s_sleep(8);
    }
    __syncthreads();

    const int rank = ticket - (TOT_TILES - TAIL);           // 0..TAIL-1
    const int chunk = (BB * NCLS * OUTR * OUTR) / TAIL;     // 6272, contiguous per block
    const float inv = 48.0f / 224.0f;
    for (int idx = rank * chunk + tid; idx < (rank + 1) * chunk; idx += 256) {
        int ox = idx % OUTR;
        int oy = (idx / OUTR) % OUTR;
        int bn = idx / (OUTR * OUTR);
        const unsigned* src = enc_logits + (size_t)bn * HW;
        float sx = (ox + 0.5f) * inv - 0.5f;
        float sy = (oy + 0.5f) * inv - 0.5f;
        int x0 = (int)floorf(sx); float fx = sx - x0;
        int y0 = (int)floorf(sy); float fy = sy - y0;
        int x0c = min(max(x0, 0), 47), x1c = min(max(x0 + 1, 0), 47);
        int y0c = min(max(y0, 0), 47), y1c = min(max(y0 + 1, 0), 47);
        float v00 = dec_f(load_agent(src + y0c * 48 + x0c));
        float v01 = dec_f(load_agent(src + y0c * 48 + x1c));
        float v10 = dec_f(load_agent(src + y1c * 48 + x0c));
        float v11 = dec_f(load_agent(src + y1c * 48 + x1c));
        float v = (1.f - fy) * ((1.f - fx) * v00 + fx * v01) + fy * ((1.f - fx) * v10 + fx * v11);
        if ((bn & 3) == 0 && v == -INFINITY) v = 0.f;
        out[idx] = v;
    }
}

// ---------------- launch ------------------------------------------------------------------------
extern "C" void kernel_launch(void* const* d_in, const int* in_sizes, int n_in,
                              void* d_out, int out_size, void* d_ws, size_t ws_size,
                              hipStream_t stream) {
    const float* emb = (const float*)d_in[0];   // (2,9,256,48,48) fp32
    const float* pm  = (const float*)d_in[1];   // (2,8,4,48,48) fp32
    float* out = (float*)d_out;                 // (2,4,224,224) fp32

    char* ws = (char*)d_ws;
    const size_t normed_bytes = (size_t)BB * MM * HW * DD * 2;   // 21,233,664
    __hip_bfloat16* normed = (__hip_bfloat16*)(ws);
    unsigned*       enc    = (unsigned*)(ws + normed_bytes);     // BB*NCLS*HW uints + 1 counter
    unsigned*       cnt    = enc + BB * NCLS * HW;

    knorm<<<dim3(HW / 32, BB * MM), 256, 0, stream>>>(emb, normed, enc);
    kgemm<<<dim3(144, 18, BB), 256, 0, stream>>>((const unsigned short*)normed, pm, enc, cnt, out);
}

// Round 7
// 142.826 us; speedup vs baseline: 1.9968x; 1.9968x over previous
//
#include <hip/hip_runtime.h>
#include <hip/hip_bf16.h>
#include <math.h>

// Problem constants
#define BB 2
#define MM 9          // 1 query + 8 supports
#define MS 8
#define DD 256
#define HW 2304       // 48*48
#define NCLS 4
#define OUTR 224

typedef float floatx4 __attribute__((ext_vector_type(4)));
typedef __bf16 bf16x8 __attribute__((ext_vector_type(8)));
typedef unsigned short ushortx8 __attribute__((ext_vector_type(8)));

// order-preserving float <-> uint encode for atomicMax
__device__ __forceinline__ unsigned enc_f(float f) {
    unsigned u = __float_as_uint(f);
    return (u & 0x80000000u) ? ~u : (u | 0x80000000u);
}
__device__ __forceinline__ float dec_f(unsigned k) {
    unsigned u = (k & 0x80000000u) ? (k & 0x7FFFFFFFu) : ~k;
    return __uint_as_float(u);
}

// ---------------- Kernel 1 (v3): v1 structure (32-pix tiles, 4 blocks/CU) + float4 loads -------
// in : emb[bm][d][pix] fp32 ; out: normed[bm][pix][d] bf16. Also zero-inits enc_logits.
__global__ __launch_bounds__(256) void knorm(const float* __restrict__ emb,
                                             __hip_bfloat16* __restrict__ outp,
                                             unsigned* __restrict__ enc_logits) {
    __shared__ float tile[256][33];   // [d][pix], +1 pad
    __shared__ float psum[8][32];
    __shared__ float sscale[32];
    const int bm   = blockIdx.y;
    const int pix0 = blockIdx.x * 32;
    const int tid  = threadIdx.x;

    // fused init of encoded logits (BB*NCLS*HW = 18432 entries; key 0 < any enc(finite))
    int flat = (blockIdx.y * gridDim.x + blockIdx.x) * 256 + tid;
    if (flat < BB * NCLS * HW) enc_logits[flat] = 0u;

    // ---- load: 8 iterations of float4; per iter wave covers 8 d-rows x 128B ----
    const float* src = emb + (size_t)bm * DD * HW + pix0;
    {
        const int dr = tid >> 3;          // 0..31
        const int p4 = (tid & 7) * 4;     // 0..28
#pragma unroll
        for (int r = 0; r < 8; ++r) {
            int d = r * 32 + dr;
            floatx4 v = *(const floatx4*)(src + (size_t)d * HW + p4);
            float* t = &tile[d][p4];
            t[0] = v[0]; t[1] = v[1]; t[2] = v[2]; t[3] = v[3];
        }
    }
    __syncthreads();
    // ---- sum of squares: thread (chunk=dr, pix=pc) sums 32 d's ----
    {
        const int pc = tid & 31;
        const int dr = tid >> 5;          // 0..7
        float ss = 0.f;
#pragma unroll
        for (int s = 0; s < 32; ++s) {
            float v = tile[dr * 32 + s][pc];
            ss += v * v;
        }
        psum[dr][pc] = ss;
    }
    __syncthreads();
    if (tid < 32) {
        float t = 0.f;
#pragma unroll
        for (int c = 0; c < 8; ++c) t += psum[c][tid];
        sscale[tid] = 1.0f / fmaxf(sqrtf(t), 1e-12f);
    }
    __syncthreads();
    // ---- store: thread=d, r=pixel; 512B dense per r across the block ----
    __hip_bfloat16* dst = outp + (size_t)bm * HW * DD + (size_t)pix0 * DD;
#pragma unroll
    for (int r = 0; r < 32; ++r) {
        float v = tile[tid][r] * sscale[r];
        dst[(size_t)r * DD + tid] = __float2bfloat16(v);
    }
}

// ---------------- Kernel 2: bf16 MFMA GEMM + fused mask + per-class masked max + atomicMax -----
__device__ __forceinline__ void gld16(const unsigned short* g, unsigned short* l) {
    __builtin_amdgcn_global_load_lds((__attribute__((address_space(1))) void*)g,
                                     (__attribute__((address_space(3))) void*)l, 16, 0, 0);
}

#define BK 64
#define REDSTRIDE 132
// LDS: staging As+Bs = 32768 B; epilogue red[2][32][132] f32 = 33792 B (union)
#define SMEM_BYTES 33792

// grid: (144 = m*18 + kt, 18 = row tile, 2 = b); block 256 (4 waves)
__global__ __launch_bounds__(256, 4) void kgemm(const unsigned short* __restrict__ normed,
                                                const float* __restrict__ pm,
                                                unsigned* __restrict__ enc_logits) {
    __shared__ __attribute__((aligned(16))) unsigned char smem[SMEM_BYTES];
    unsigned short* As = (unsigned short*)smem;          // [128][64] row-major, chunk-swizzled
    unsigned short* Bs = As + 128 * 64;
    float* red = (float*)smem;                           // union (staging dead in epilogue)

    const int ct = blockIdx.x;       // 0..143
    const int rt = blockIdx.y;       // 0..17
    const int b  = blockIdx.z;
    const int m  = ct / 18;          // support index 0..7
    const int kt = ct % 18;          // col tile within support

    const int tid  = threadIdx.x;
    const int lane = tid & 63;
    const int wave = tid >> 6;
    const int wr = wave >> 1, wc = wave & 1;
    const int lrow = lane & 15;
    const int quad = lane >> 4;      // 0..3

    const unsigned short* A  = normed + (size_t)(b * MM) * (HW * DD) + (size_t)(rt * 128) * DD;
    const unsigned short* Bp = normed + (size_t)(b * MM + 1 + m) * (HW * DD) + (size_t)(kt * 128) * DD;

    // ---- fused mask bits ----
    const float* pmB = pm + (size_t)(b * MS + m) * NCLS * HW;
    int mj[4];
#pragma unroll
    for (int j = 0; j < 4; ++j) {
        int kp = kt * 128 + wc * 64 + j * 16 + lrow;
        float p1 = pmB[HW + kp], p2 = pmB[2 * HW + kp], p3 = pmB[3 * HW + kp];
        mj[j] = ((p1 + p2 + p3 == 0.0f) ? 1 : 0) | (p1 != 0.0f ? 2 : 0) |
                (p2 != 0.0f ? 4 : 0) | (p3 != 0.0f ? 8 : 0);
    }

    // staging: lane l covers row r0+(l>>3), phys chunk p=l&7 holds logical chunk p^(row&7).
    const int srq  = lane >> 3;                  // row within 8-row group
    const int scol = ((lane & 7) ^ srq) * 8;     // logical chunk * 8 elems

    floatx4 zero = {0.f, 0.f, 0.f, 0.f};
    floatx4 acc[4][4];
#pragma unroll
    for (int i = 0; i < 4; ++i)
#pragma unroll
        for (int j = 0; j < 4; ++j) acc[i][j] = zero;

    for (int k0 = 0; k0 < DD; k0 += BK) {
#pragma unroll
        for (int q = 0; q < 4; ++q) {
            int row = wave * 32 + q * 8 + srq;
            gld16(A  + (size_t)row * DD + k0 + scol, As + (wave * 4 + q) * 512);
            gld16(Bp + (size_t)row * DD + k0 + scol, Bs + (wave * 4 + q) * 512);
        }
        __syncthreads();
#pragma unroll
        for (int kk = 0; kk < 2; ++kk) {
            bf16x8 af[4], bfr[4];
#pragma unroll
            for (int i = 0; i < 4; ++i) {
                int ar = wr * 64 + i * 16 + lrow;
                int br = wc * 64 + i * 16 + lrow;
                int pcA = (kk * 4 + quad) ^ (ar & 7);   // phys chunk (swizzled)
                int pcB = (kk * 4 + quad) ^ (br & 7);
                af[i]  = __builtin_bit_cast(bf16x8, *(const ushortx8*)(As + ar * 64 + pcA * 8));
                bfr[i] = __builtin_bit_cast(bf16x8, *(const ushortx8*)(Bs + br * 64 + pcB * 8));
            }
#pragma unroll
            for (int i = 0; i < 4; ++i)
#pragma unroll
                for (int j = 0; j < 4; ++j)
                    acc[i][j] = __builtin_amdgcn_mfma_f32_16x16x32_bf16(af[i], bfr[j], acc[i][j], 0, 0, 0);
        }
        __syncthreads();
    }

    // ---- epilogue: per-class masked max, LDS transpose-reduce, atomicMax ----
    const int col32 = wc * 16 + lrow;

#pragma unroll
    for (int p = 0; p < 2; ++p) {
        if (p) __syncthreads();
        bool bit[2][4];
#pragma unroll
        for (int nn = 0; nn < 2; ++nn) {
            int n = p * 2 + nn;
#pragma unroll
            for (int j = 0; j < 4; ++j) bit[nn][j] = (mj[j] >> n) & 1;
        }
#pragma unroll
        for (int nn = 0; nn < 2; ++nn) {
#pragma unroll
            for (int i = 0; i < 4; ++i) {
                floatx4 o;
#pragma unroll
                for (int r = 0; r < 4; ++r) {
                    float t0 = bit[nn][0] ? acc[i][0][r] : -INFINITY;
                    float t1 = bit[nn][1] ? acc[i][1][r] : -INFINITY;
                    float t2 = bit[nn][2] ? acc[i][2][r] : -INFINITY;
                    float t3 = bit[nn][3] ? acc[i][3][r] : -INFINITY;
                    o[r] = fmaxf(fmaxf(t0, t1), fmaxf(t2, t3));
                }
                int rowbase = wr * 64 + i * 16 + quad * 4;
                *(floatx4*)(red + ((size_t)(nn * 32 + col32)) * REDSTRIDE + rowbase) = o;
            }
        }
        __syncthreads();
        {
            int nn  = tid >> 7;
            int row = tid & 127;
            float v = -INFINITY;
#pragma unroll
            for (int c = 0; c < 32; ++c)
                v = fmaxf(v, red[((size_t)(nn * 32 + c)) * REDSTRIDE + row]);
            int n = p * 2 + nn;
            atomicMax(enc_logits + ((size_t)b * NCLS + n) * HW + rt * 128 + row, enc_f(v));
        }
    }
}

// ---------------- Kernel 3: bilinear 48 -> 224 (decode) + -inf fix on ch 0 ---------------------
__global__ __launch_bounds__(256) void kresize(const unsigned* __restrict__ enc_logits,
                                               float* __restrict__ out) {
    int idx = blockIdx.x * 256 + threadIdx.x;   // BB*NCLS*224*224
    if (idx >= BB * NCLS * OUTR * OUTR) return;
    int ox = idx % OUTR;
    int oy = (idx / OUTR) % OUTR;
    int bn = idx / (OUTR * OUTR);
    const unsigned* src = enc_logits + (size_t)bn * HW;
    const float inv = 48.0f / 224.0f;
    float sx = (ox + 0.5f) * inv - 0.5f;
    float sy = (oy + 0.5f) * inv - 0.5f;
    int x0 = (int)floorf(sx); float fx = sx - x0;
    int y0 = (int)floorf(sy); float fy = sy - y0;
    int x0c = min(max(x0, 0), 47), x1c = min(max(x0 + 1, 0), 47);
    int y0c = min(max(y0, 0), 47), y1c = min(max(y0 + 1, 0), 47);
    float v00 = dec_f(src[y0c * 48 + x0c]), v01 = dec_f(src[y0c * 48 + x1c]);
    float v10 = dec_f(src[y1c * 48 + x0c]), v11 = dec_f(src[y1c * 48 + x1c]);
    float v = (1.f - fy) * ((1.f - fx) * v00 + fx * v01) + fy * ((1.f - fx) * v10 + fx * v11);
    if ((bn & 3) == 0 && v == -INFINITY) v = 0.f;
    out[idx] = v;
}

// ---------------- launch ------------------------------------------------------------------------
extern "C" void kernel_launch(void* const* d_in, const int* in_sizes, int n_in,
                              void* d_out, int out_size, void* d_ws, size_t ws_size,
                              hipStream_t stream) {
    const float* emb = (const float*)d_in[0];   // (2,9,256,48,48) fp32
    const float* pm  = (const float*)d_in[1];   // (2,8,4,48,48) fp32
    float* out = (float*)d_out;                 // (2,4,224,224) fp32

    char* ws = (char*)d_ws;
    const size_t normed_bytes = (size_t)BB * MM * HW * DD * 2;   // 21,233,664
    __hip_bfloat16* normed = (__hip_bfloat16*)(ws);
    unsigned*       enc    = (unsigned*)(ws + normed_bytes);     // BB*NCLS*HW uints

    knorm<<<dim3(HW / 32, BB * MM), 256, 0, stream>>>(emb, normed, enc);
    kgemm<<<dim3(144, 18, BB), 256, 0, stream>>>((const unsigned short*)normed, pm, enc);
    kresize<<<(BB * NCLS * OUTR * OUTR + 255) / 256, 256, 0, stream>>>(enc, out);
}